// Round 15
// baseline (274.949 us; speedup 1.0000x reference)
//
#include <hip/hip_runtime.h>

typedef __attribute__((ext_vector_type(8))) short short8;
typedef __attribute__((ext_vector_type(4))) float f32x4;

// ---------- helpers ----------
__device__ __forceinline__ unsigned short f2bf(float f) {
  unsigned u = __builtin_bit_cast(unsigned, f);
  u += 0x7fffu + ((u >> 16) & 1u);   // RNE
  return (unsigned short)(u >> 16);
}
// pack two f32 -> two bf16 (RTZ) in ONE v_perm_b32: bytes [p1.hi16 : p0.hi16]
__device__ __forceinline__ unsigned pack_bf2_rtz(float p0, float p1) {
  return __builtin_amdgcn_perm(__builtin_bit_cast(unsigned, p1),
                               __builtin_bit_cast(unsigned, p0), 0x07060302u);
}

#define GLDS16(g, l)                                                          \
  __builtin_amdgcn_global_load_lds(                                           \
      (const __attribute__((address_space(1))) void*)(g),                     \
      (__attribute__((address_space(3))) void*)(l), 16, 0, 0)

// Q pre-scale: HEAD_DIM^-0.5 * log2(e), so softmax uses exp2 directly.
#define QSCALE 0.18033688011112042f

// ---------- cast x (fp32 -> bf16), vectorized ----------
__global__ void cast_x_bf16(const float4* __restrict__ in,
                            ushort4* __restrict__ out, int n4) {
  int i = blockIdx.x * blockDim.x + threadIdx.x;
  if (i >= n4) return;
  float4 v = in[i];
  ushort4 o;
  o.x = f2bf(v.x); o.y = f2bf(v.y); o.z = f2bf(v.z); o.w = f2bf(v.w);
  out[i] = o;
}

// ---------- fused transpose+convert of all weights (one launch) ----------
__global__ void transpose_cvt_all(const float* __restrict__ Wq,
                                  const float* __restrict__ Wk,
                                  const float* __restrict__ Wv,
                                  const float* __restrict__ Wo,
                                  unsigned short* __restrict__ Wcat,
                                  unsigned short* __restrict__ Wot) {
  __shared__ float tile[32][33];
  const int z = blockIdx.z;
  int bx = blockIdx.x;
  const float* in;
  unsigned short* out;
  int N;
  if (z == 0)      { in = Wq; out = Wcat;               N = 1024; }
  else if (z == 1) { in = Wo; out = Wot;                N = 1024; }
  else {
    if (bx < 2)      { in = Wk; out = Wcat + 1024 * 1024; N = 64; }
    else if (bx < 4) { in = Wv; out = Wcat + 1088 * 1024; N = 64; bx -= 2; }
    else return;
  }
  const int K = 1024;
  const int n0 = bx * 32, k0 = blockIdx.y * 32;
  const int tx = threadIdx.x, ty = threadIdx.y;  // block (32,8)
#pragma unroll
  for (int i = 0; i < 4; ++i)
    tile[ty + 8 * i][tx] = in[(size_t)(k0 + ty + 8 * i) * N + n0 + tx];
  __syncthreads();
#pragma unroll
  for (int i = 0; i < 4; ++i)
    out[(size_t)(n0 + ty + 8 * i) * K + k0 + tx] = f2bf(tile[tx][ty + 8 * i]);
}

// ---------- transpose V: Vr [b*2048+t][64] -> Vt [b][64][2048] ----------
__global__ void transpose_v(const unsigned short* __restrict__ Vr,
                            unsigned short* __restrict__ Vt) {
  __shared__ unsigned short tile[32][34];
  const int t0 = blockIdx.x * 32;
  const int d0 = blockIdx.y * 32;
  const int b = blockIdx.z;
  const int tx = threadIdx.x, ty = threadIdx.y;  // block (32,8)
#pragma unroll
  for (int i = 0; i < 4; ++i)
    tile[ty + 8 * i][tx] =
        Vr[(size_t)(b * 2048 + t0 + ty + 8 * i) * 64 + d0 + tx];
  __syncthreads();
#pragma unroll
  for (int i = 0; i < 4; ++i)
    Vt[((size_t)b * 64 + d0 + ty + 8 * i) * 2048 + t0 + tx] =
        tile[tx][ty + 8 * i];
}

// ---------- GEMM: C[M][N] = A[M][K](bf16) * Bt[N][K](bf16)^T ----------
// m97 structure + bijective XCD-aware block swizzle (grid %8 == 0).
template <int EPI>
__global__ __launch_bounds__(256) void gemm_bt(
    const unsigned short* __restrict__ A, const unsigned short* __restrict__ Bt,
    unsigned short* __restrict__ Cq, unsigned short* __restrict__ Ck,
    unsigned short* __restrict__ Cv, float* __restrict__ Cf, int N, int K) {
  __shared__ __align__(16) unsigned short As[128 * 64];
  __shared__ __align__(16) unsigned short Bs[128 * 64];
  const int tid = threadIdx.x;
  const int w = tid >> 6, lane = tid & 63;
  const int nwg = gridDim.x * gridDim.y;
  const int lid = blockIdx.y * gridDim.x + blockIdx.x;
  const int cpx = nwg >> 3;
  const int swz = (lid & 7) * cpx + (lid >> 3);
  const int m0 = (swz / gridDim.x) * 128, n0 = (swz % gridDim.x) * 128;
  const int wm = (w >> 1) * 64, wn = (w & 1) * 64;
  const int g = lane >> 4, c = lane & 15;
  const int lr = lane >> 3, lc = (lane & 7) * 8;

  f32x4 acc[4][4] = {};

  for (int k0 = 0; k0 < K; k0 += 64) {
#pragma unroll
    for (int i = 0; i < 4; ++i) {
      int ci = w * 4 + i;  // 1KB chunk: rows 8ci..8ci+7
      GLDS16(A + (size_t)(m0 + ci * 8 + lr) * K + k0 + lc, As + ci * 512);
      GLDS16(Bt + (size_t)(n0 + ci * 8 + lr) * K + k0 + lc, Bs + ci * 512);
    }
    __syncthreads();
#pragma unroll
    for (int kk = 0; kk < 2; ++kk) {
      const int col = kk * 32 + g * 8;
      short8 av[4], bv[4];
#pragma unroll
      for (int mi = 0; mi < 4; ++mi)
        av[mi] = *(const short8*)(As + (wm + mi * 16 + c) * 64 + col);
#pragma unroll
      for (int ni = 0; ni < 4; ++ni)
        bv[ni] = *(const short8*)(Bs + (wn + ni * 16 + c) * 64 + col);
#pragma unroll
      for (int mi = 0; mi < 4; ++mi)
#pragma unroll
        for (int ni = 0; ni < 4; ++ni)
          acc[mi][ni] = __builtin_amdgcn_mfma_f32_16x16x32_bf16(
              av[mi], bv[ni], acc[mi][ni], 0, 0, 0);
    }
    __syncthreads();
  }

#pragma unroll
  for (int mi = 0; mi < 4; ++mi) {
#pragma unroll
    for (int ni = 0; ni < 4; ++ni) {
      f32x4 a = acc[mi][ni];
      const int col = n0 + wn + ni * 16 + c;
#pragma unroll
      for (int r = 0; r < 4; ++r) {
        const int row = m0 + wm + mi * 16 + g * 4 + r;
        float v = a[r];
        if (EPI == 0) {
          if (col < 1024)
            Cq[(size_t)row * 1024 + col] = f2bf(v * QSCALE);
          else if (col < 1088)
            Ck[(size_t)row * 64 + (col - 1024)] = f2bf(v);
          else  // V coalesced [row][64]; transposed by transpose_v
            Cv[(size_t)row * 64 + (col - 1088)] = f2bf(v);
        } else {
          Cf[(size_t)row * N + col] = v;
        }
      }
    }
  }
}

// ---------- causal multi-query flash attention, v11 ----------
// R9 structure (best-known) with V de-staged: K double-buffered in LDS
// (QK^T on the fast path, 1 barrier/iter); V fragments read DIRECTLY from
// global (L1/L2-resident, proven-correct R14 addressing), ISSUED at iter
// top so QK^T+softmax hides their latency (T14). LDS 34.8 KB -> 4 blocks/CU
// = 16 waves/CU. 4 waves = 1 head, q=32/wave, KVBLK=64, qtile=128; grid
// 1024, longest blocks first + backfill. Swapped QK^T lane-local softmax;
// defer-max THR=8; l via ones-MFMA; P-pack v_perm RTZ.
__global__ __launch_bounds__(256, 4) void attn_mqa(
    const unsigned short* __restrict__ Q, const unsigned short* __restrict__ Kb,
    const unsigned short* __restrict__ Vt, unsigned short* __restrict__ Oc) {
  __shared__ __align__(16) unsigned short Kl[2][64 * 64];
  __shared__ __align__(16) unsigned short Pl[4][32 * 72];
  const int tid = threadIdx.x;
  const int w = tid >> 6, lane = tid & 63;
  const int bid = blockIdx.x;            // 0..1023
  const int b = bid & 3;
  const int h = (bid >> 2) & 15;
  const int qidx = (bid >> 6) & 15;
  const int qt = 15 - qidx;              // long blocks first in dispatch order
  const int g = lane >> 4, c = lane & 15;
  const int swr = (c & 7) * 8;            // K read xor (shorts)
  const int srow8 = tid >> 3;             // staging row 0..31 (pass adds 32)
  const int scs = ((tid & 7) ^ (srow8 & 7)) * 8;  // swizzled source col
  const unsigned short* Kbase = Kb + (size_t)b * 2048 * 64;
  const unsigned short* Vbase = Vt + (size_t)b * 64 * 2048;
  unsigned short* pw = Pl[w];
  unsigned* pd = (unsigned*)pw;           // dword view, row stride 36

  short8 ones;
#pragma unroll
  for (int j = 0; j < 8; ++j) ones[j] = (short)0x3F80;  // bf16 1.0

  const int qb = qt * 128 + w * 32;       // wave's first q row

  // Q fragments (B-operand: col=c, k=g*8+j) for both subtiles, pre-scaled
  short8 qf[2][2];
#pragma unroll
  for (int u = 0; u < 2; ++u)
#pragma unroll
    for (int kk = 0; kk < 2; ++kk)
      qf[u][kk] = *(const short8*)(Q + (size_t)(b * 2048 + qb + u * 16 + c) *
                                           1024 + h * 64 + kk * 32 + g * 8);

  f32x4 po[2][4] = {};
  f32x4 lac[2] = {};
  float m[2] = {-1e30f, -1e30f};

  // prologue: stage K tile 0 into buf 0 (each thread: 2x16B)
  const unsigned short* kpf = Kbase + (size_t)srow8 * 64 + scs;
  GLDS16(kpf, &Kl[0][0] + tid * 8);
  GLDS16(kpf + 2048, &Kl[0][0] + tid * 8 + 2048);
  kpf += 4096;
  // per-lane V fragment pointer (direct global; advances 64 cols/iter)
  const unsigned short* vfp = Vbase + (size_t)c * 2048 + g * 8;
  int cur = 0;
  const int nit = 2 * qt + 2;

  for (int it = 0; it < nit; ++it) {
    __syncthreads();  // K buf[cur] staged; prev reads of cur^1 done

    if (it < nit - 1) {  // prefetch next K tile into cur^1
      unsigned short* kd = &Kl[cur ^ 1][0] + tid * 8;
      GLDS16(kpf, kd);
      GLDS16(kpf + 2048, kd + 2048);
      kpf += 4096;
    }

    // EARLY-ISSUE V fragment loads (global, L1/L2-hit); consumed in PV
    // after QK^T+softmax -> latency hidden (T14 issue-early/write-late).
    short8 vfr0[4], vfr1[4];
#pragma unroll
    for (int fd = 0; fd < 4; ++fd) {
      vfr0[fd] = *(const short8*)(vfp + (size_t)fd * 32768);
      vfr1[fd] = *(const short8*)(vfp + (size_t)fd * 32768 + 32);
    }

    const unsigned short* Kt = &Kl[cur][0];
    const int kv0 = it * 64;

    // S^T = K Q^T for both subtiles; each kf read feeds 2 MFMAs
    f32x4 s[2][4] = {};
    __builtin_amdgcn_s_setprio(1);
#pragma unroll
    for (int kk = 0; kk < 2; ++kk) {
      const int col = (kk * 32 + g * 8) ^ swr;
#pragma unroll
      for (int f = 0; f < 4; ++f) {
        short8 kf = *(const short8*)(Kt + (f * 16 + c) * 64 + col);
        s[0][f] = __builtin_amdgcn_mfma_f32_16x16x32_bf16(kf, qf[0][kk],
                                                          s[0][f], 0, 0, 0);
        s[1][f] = __builtin_amdgcn_mfma_f32_16x16x32_bf16(kf, qf[1][kk],
                                                          s[1][f], 0, 0, 0);
      }
    }
    __builtin_amdgcn_s_setprio(0);

    float pm[2];
#pragma unroll
    for (int u = 0; u < 2; ++u) {
      if (kv0 + 63 > qb + u * 16) {  // mask needed (diagonal or beyond)
        const int qi = qb + u * 16 + c;
#pragma unroll
        for (int f = 0; f < 4; ++f)
#pragma unroll
          for (int r = 0; r < 4; ++r)
            if (kv0 + f * 16 + g * 4 + r > qi) s[u][f][r] = -1e30f;
      }
      // lane-local max over 16 kv values (max3-fusable tree)
      const float t0 = fmaxf(fmaxf(s[u][0][0], s[u][0][1]), s[u][0][2]);
      const float t1 = fmaxf(fmaxf(s[u][0][3], s[u][1][0]), s[u][1][1]);
      const float t2 = fmaxf(fmaxf(s[u][1][2], s[u][1][3]), s[u][2][0]);
      const float t3 = fmaxf(fmaxf(s[u][2][1], s[u][2][2]), s[u][2][3]);
      const float t4 = fmaxf(fmaxf(s[u][3][0], s[u][3][1]), s[u][3][2]);
      const float u0 = fmaxf(fmaxf(t0, t1), t2);
      const float u1 = fmaxf(fmaxf(t3, t4), s[u][3][3]);
      pm[u] = fmaxf(u0, u1);
    }

    // defer-max: rescale only when some row's max grew past THR=8 (log2)
    if (!__all(pm[0] <= m[0] + 8.0f && pm[1] <= m[1] + 8.0f)) {
#pragma unroll
      for (int u = 0; u < 2; ++u) {
        float pmu = fmaxf(pm[u], __shfl_xor(pm[u], 16, 64));
        pmu = fmaxf(pmu, __shfl_xor(pmu, 32, 64));    // full max for q=c
        const float mn = fmaxf(m[u], pmu);
        const float al = __builtin_amdgcn_exp2f(m[u] - mn);
        m[u] = mn;
#pragma unroll
        for (int r = 0; r < 4; ++r) {
          const float ar = __shfl(al, g * 4 + r, 64);  // alpha for row g*4+r
          lac[u][r] *= ar;
#pragma unroll
          for (int fd = 0; fd < 4; ++fd) po[u][fd][r] *= ar;
        }
      }
    }

    // P = exp2(S - m): v_perm RTZ pack, bounce [q][kv] through wave LDS
#pragma unroll
    for (int u = 0; u < 2; ++u) {
#pragma unroll
      for (int f = 0; f < 4; ++f) {
        const float p0 = __builtin_amdgcn_exp2f(s[u][f][0] - m[u]);
        const float p1 = __builtin_amdgcn_exp2f(s[u][f][1] - m[u]);
        const float p2 = __builtin_amdgcn_exp2f(s[u][f][2] - m[u]);
        const float p3 = __builtin_amdgcn_exp2f(s[u][f][3] - m[u]);
        uint2 pk;
        pk.x = pack_bf2_rtz(p0, p1);
        pk.y = pack_bf2_rtz(p2, p3);
        *(uint2*)(pd + (u * 16 + c) * 36 + f * 8 + g * 2) = pk;
      }
    }

    // O += P V ; l += P 1  (V from early-issued registers)
    __builtin_amdgcn_s_setprio(1);
#pragma unroll
    for (int kk = 0; kk < 2; ++kk) {
      short8 pa0 = *(const short8*)(pw + c * 72 + kk * 32 + g * 8);
      short8 pa1 = *(const short8*)(pw + (16 + c) * 72 + kk * 32 + g * 8);
      lac[0] = __builtin_amdgcn_mfma_f32_16x16x32_bf16(pa0, ones, lac[0], 0, 0, 0);
      lac[1] = __builtin_amdgcn_mfma_f32_16x16x32_bf16(pa1, ones, lac[1], 0, 0, 0);
#pragma unroll
      for (int fd = 0; fd < 4; ++fd) {
        short8 vf = kk ? vfr1[fd] : vfr0[fd];
        po[0][fd] = __builtin_amdgcn_mfma_f32_16x16x32_bf16(pa0, vf, po[0][fd],
                                                            0, 0, 0);
        po[1][fd] = __builtin_amdgcn_mfma_f32_16x16x32_bf16(pa1, vf, po[1][fd],
                                                            0, 0, 0);
      }
    }
    __builtin_amdgcn_s_setprio(0);
    vfp += 64;
    cur ^= 1;
  }

  // epilogue: O / l
#pragma unroll
  for (int u = 0; u < 2; ++u) {
#pragma unroll
    for (int r = 0; r < 4; ++r) {
      const float inv = __builtin_amdgcn_rcpf(lac[u][r]);
      const int trow = qb + u * 16 + g * 4 + r;
#pragma unroll
      for (int fd = 0; fd < 4; ++fd)
        Oc[(size_t)(b * 2048 + trow) * 1024 + h * 64 + fd * 16 + c] =
            f2bf(po[u][fd][r] * inv);
    }
  }
}

// ---------- launch ----------
extern "C" void kernel_launch(void* const* d_in, const int* in_sizes, int n_in,
                              void* d_out, int out_size, void* d_ws,
                              size_t ws_size, hipStream_t stream) {
  const float* x = (const float*)d_in[0];
  const float* Wq = (const float*)d_in[1];
  const float* Wk = (const float*)d_in[2];
  const float* Wv = (const float*)d_in[3];
  const float* Wo = (const float*)d_in[4];
  float* out = (float*)d_out;

  char* ws = (char*)d_ws;
  unsigned short* xb   = (unsigned short*)ws;                          // 16 MB
  unsigned short* Qb   = (unsigned short*)(ws + (size_t)(16u << 20));  // 16 MB
  unsigned short* Attn = (unsigned short*)(ws + (size_t)(32u << 20));  // 16 MB
  unsigned short* Wcat = (unsigned short*)(ws + (size_t)(48u << 20));  // 2.25 MB
  unsigned short* Wot  = (unsigned short*)(ws + (size_t)(48u << 20) + 2359296);
  unsigned short* Kb   = (unsigned short*)(ws + (size_t)(48u << 20) + 2359296 + 2097152);
  unsigned short* Vtb  = (unsigned short*)(ws + (size_t)(48u << 20) + 2359296 + 2097152 + 1048576);
  unsigned short* Vrow = Attn;  // V staging row-major; dead before attn writes O

  // 1) cast x, fused weight transposes
  cast_x_bf16<<<8192, 256, 0, stream>>>((const float4*)x, (ushort4*)xb, 2097152);
  transpose_cvt_all<<<dim3(32, 32, 3), dim3(32, 8), 0, stream>>>(Wq, Wk, Wv, Wo,
                                                                 Wcat, Wot);

  // 2) fused QKV GEMM (V written coalesced), then V transpose
  gemm_bt<0><<<dim3(9, 64), 256, 0, stream>>>(xb, Wcat, Qb, Kb, Vrow, nullptr,
                                              1152, 1024);
  transpose_v<<<dim3(64, 2, 4), dim3(32, 8), 0, stream>>>(Vrow, Vtb);

  // 3) causal MQA flash attention (K staged, V direct+early, 4 blocks/CU)
  attn_mqa<<<1024, 256, 0, stream>>>(Qb, Kb, Vtb, Attn);

  // 4) output projection: [8192][1024] x [1024][1024]^T -> fp32 d_out
  gemm_bt<1><<<dim3(8, 64), 256, 0, stream>>>(Attn, Wot, nullptr, nullptr,
                                              nullptr, out, 1024, 1024);
}

// Round 16
// 146.880 us; speedup vs baseline: 1.8719x; 1.8719x over previous
//
#include <hip/hip_runtime.h>

typedef __attribute__((ext_vector_type(8))) short short8;
typedef __attribute__((ext_vector_type(4))) float f32x4;

// ---------- helpers ----------
__device__ __forceinline__ unsigned short f2bf(float f) {
  unsigned u = __builtin_bit_cast(unsigned, f);
  u += 0x7fffu + ((u >> 16) & 1u);   // RNE
  return (unsigned short)(u >> 16);
}
// pack two f32 -> two bf16 (RTZ) in ONE v_perm_b32: bytes [p1.hi16 : p0.hi16]
__device__ __forceinline__ unsigned pack_bf2_rtz(float p0, float p1) {
  return __builtin_amdgcn_perm(__builtin_bit_cast(unsigned, p1),
                               __builtin_bit_cast(unsigned, p0), 0x07060302u);
}

#define GLDS16(g, l)                                                          \
  __builtin_amdgcn_global_load_lds(                                           \
      (const __attribute__((address_space(1))) void*)(g),                     \
      (__attribute__((address_space(3))) void*)(l), 16, 0, 0)

// Q pre-scale: HEAD_DIM^-0.5 * log2(e), so softmax uses exp2 directly.
#define QSCALE 0.18033688011112042f

// ---------- cast x (fp32 -> bf16), vectorized ----------
__global__ void cast_x_bf16(const float4* __restrict__ in,
                            ushort4* __restrict__ out, int n4) {
  int i = blockIdx.x * blockDim.x + threadIdx.x;
  if (i >= n4) return;
  float4 v = in[i];
  ushort4 o;
  o.x = f2bf(v.x); o.y = f2bf(v.y); o.z = f2bf(v.z); o.w = f2bf(v.w);
  out[i] = o;
}

// ---------- fused transpose+convert of all weights (one launch) ----------
__global__ void transpose_cvt_all(const float* __restrict__ Wq,
                                  const float* __restrict__ Wk,
                                  const float* __restrict__ Wv,
                                  const float* __restrict__ Wo,
                                  unsigned short* __restrict__ Wcat,
                                  unsigned short* __restrict__ Wot) {
  __shared__ float tile[32][33];
  const int z = blockIdx.z;
  int bx = blockIdx.x;
  const float* in;
  unsigned short* out;
  int N;
  if (z == 0)      { in = Wq; out = Wcat;               N = 1024; }
  else if (z == 1) { in = Wo; out = Wot;                N = 1024; }
  else {
    if (bx < 2)      { in = Wk; out = Wcat + 1024 * 1024; N = 64; }
    else if (bx < 4) { in = Wv; out = Wcat + 1088 * 1024; N = 64; bx -= 2; }
    else return;
  }
  const int K = 1024;
  const int n0 = bx * 32, k0 = blockIdx.y * 32;
  const int tx = threadIdx.x, ty = threadIdx.y;  // block (32,8)
#pragma unroll
  for (int i = 0; i < 4; ++i)
    tile[ty + 8 * i][tx] = in[(size_t)(k0 + ty + 8 * i) * N + n0 + tx];
  __syncthreads();
#pragma unroll
  for (int i = 0; i < 4; ++i)
    out[(size_t)(n0 + ty + 8 * i) * K + k0 + tx] = f2bf(tile[tx][ty + 8 * i]);
}

// ---------- transpose V: Vr [b*2048+t][64] -> Vt [b][64][2048] ----------
__global__ void transpose_v(const unsigned short* __restrict__ Vr,
                            unsigned short* __restrict__ Vt) {
  __shared__ unsigned short tile[32][34];
  const int t0 = blockIdx.x * 32;
  const int d0 = blockIdx.y * 32;
  const int b = blockIdx.z;
  const int tx = threadIdx.x, ty = threadIdx.y;  // block (32,8)
#pragma unroll
  for (int i = 0; i < 4; ++i)
    tile[ty + 8 * i][tx] =
        Vr[(size_t)(b * 2048 + t0 + ty + 8 * i) * 64 + d0 + tx];
  __syncthreads();
#pragma unroll
  for (int i = 0; i < 4; ++i)
    Vt[((size_t)b * 64 + d0 + ty + 8 * i) * 2048 + t0 + tx] =
        tile[tx][ty + 8 * i];
}

// ---------- GEMM: C[M][N] = A[M][K](bf16) * Bt[N][K](bf16)^T ----------
// m97 structure + bijective XCD-aware block swizzle (grid %8 == 0).
template <int EPI>
__global__ __launch_bounds__(256) void gemm_bt(
    const unsigned short* __restrict__ A, const unsigned short* __restrict__ Bt,
    unsigned short* __restrict__ Cq, unsigned short* __restrict__ Ck,
    unsigned short* __restrict__ Cv, float* __restrict__ Cf, int N, int K) {
  __shared__ __align__(16) unsigned short As[128 * 64];
  __shared__ __align__(16) unsigned short Bs[128 * 64];
  const int tid = threadIdx.x;
  const int w = tid >> 6, lane = tid & 63;
  const int nwg = gridDim.x * gridDim.y;
  const int lid = blockIdx.y * gridDim.x + blockIdx.x;
  const int cpx = nwg >> 3;
  const int swz = (lid & 7) * cpx + (lid >> 3);
  const int m0 = (swz / gridDim.x) * 128, n0 = (swz % gridDim.x) * 128;
  const int wm = (w >> 1) * 64, wn = (w & 1) * 64;
  const int g = lane >> 4, c = lane & 15;
  const int lr = lane >> 3, lc = (lane & 7) * 8;

  f32x4 acc[4][4] = {};

  for (int k0 = 0; k0 < K; k0 += 64) {
#pragma unroll
    for (int i = 0; i < 4; ++i) {
      int ci = w * 4 + i;  // 1KB chunk: rows 8ci..8ci+7
      GLDS16(A + (size_t)(m0 + ci * 8 + lr) * K + k0 + lc, As + ci * 512);
      GLDS16(Bt + (size_t)(n0 + ci * 8 + lr) * K + k0 + lc, Bs + ci * 512);
    }
    __syncthreads();
#pragma unroll
    for (int kk = 0; kk < 2; ++kk) {
      const int col = kk * 32 + g * 8;
      short8 av[4], bv[4];
#pragma unroll
      for (int mi = 0; mi < 4; ++mi)
        av[mi] = *(const short8*)(As + (wm + mi * 16 + c) * 64 + col);
#pragma unroll
      for (int ni = 0; ni < 4; ++ni)
        bv[ni] = *(const short8*)(Bs + (wn + ni * 16 + c) * 64 + col);
#pragma unroll
      for (int mi = 0; mi < 4; ++mi)
#pragma unroll
        for (int ni = 0; ni < 4; ++ni)
          acc[mi][ni] = __builtin_amdgcn_mfma_f32_16x16x32_bf16(
              av[mi], bv[ni], acc[mi][ni], 0, 0, 0);
    }
    __syncthreads();
  }

#pragma unroll
  for (int mi = 0; mi < 4; ++mi) {
#pragma unroll
    for (int ni = 0; ni < 4; ++ni) {
      f32x4 a = acc[mi][ni];
      const int col = n0 + wn + ni * 16 + c;
#pragma unroll
      for (int r = 0; r < 4; ++r) {
        const int row = m0 + wm + mi * 16 + g * 4 + r;
        float v = a[r];
        if (EPI == 0) {
          if (col < 1024)
            Cq[(size_t)row * 1024 + col] = f2bf(v * QSCALE);
          else if (col < 1088)
            Ck[(size_t)row * 64 + (col - 1024)] = f2bf(v);
          else  // V coalesced [row][64]; transposed by transpose_v
            Cv[(size_t)row * 64 + (col - 1088)] = f2bf(v);
        } else {
          Cf[(size_t)row * N + col] = v;
        }
      }
    }
  }
}

// ---------- causal multi-query flash attention, v8 (best-known, R9) ----------
// 256-thr blocks: 4 waves = 1 head x 4 q-waves, each wave q=32 (two 16-row
// subtiles). K+V double-buffered in LDS via global_load_lds (51.2 KB ->
// 3 blocks/CU); grid 1024 -> 256 blocks queue and BACKFILL as short blocks
// finish; longest blocks dispatch first. Swapped QK^T lane-local softmax;
// defer-max THR=8; l via ones-MFMA; P-pack v_perm RTZ.
// [R10: KVBLK=32 + 6-block bound -> VGPR spill, 2.7x worse. R14/R15:
//  V-direct-from-global -> scattered 16B/lane reads thrash L1, FETCH 5x,
//  latency-bound collapse. Batch-staged K+V behind 1 barrier/iter is the
//  proven optimum for this op.]
__global__ __launch_bounds__(256, 3) void attn_mqa(
    const unsigned short* __restrict__ Q, const unsigned short* __restrict__ Kb,
    const unsigned short* __restrict__ Vt, unsigned short* __restrict__ Oc) {
  __shared__ __align__(16) unsigned short Kl[2][64 * 64];
  __shared__ __align__(16) unsigned short Vl[2][64 * 64];
  __shared__ __align__(16) unsigned short Pl[4][32 * 72];
  const int tid = threadIdx.x;
  const int w = tid >> 6, lane = tid & 63;
  const int bid = blockIdx.x;            // 0..1023
  const int b = bid & 3;
  const int h = (bid >> 2) & 15;
  const int qidx = (bid >> 6) & 15;
  const int qt = 15 - qidx;              // long blocks first in dispatch order
  const int g = lane >> 4, c = lane & 15;
  const int swr = (c & 7) * 8;            // read-side xor (shorts)
  const int srow8 = tid >> 3;             // staging row 0..31 (pass adds 32)
  const int scs = ((tid & 7) ^ (srow8 & 7)) * 8;  // swizzled source col
  const unsigned short* Kbase = Kb + (size_t)b * 2048 * 64;
  const unsigned short* Vbase = Vt + (size_t)b * 64 * 2048;
  unsigned short* pw = Pl[w];
  unsigned* pd = (unsigned*)pw;           // dword view, row stride 36

  short8 ones;
#pragma unroll
  for (int j = 0; j < 8; ++j) ones[j] = (short)0x3F80;  // bf16 1.0

  const int qb = qt * 128 + w * 32;       // wave's first q row

  // Q fragments (B-operand: col=c, k=g*8+j) for both subtiles, pre-scaled
  short8 qf[2][2];
#pragma unroll
  for (int u = 0; u < 2; ++u)
#pragma unroll
    for (int kk = 0; kk < 2; ++kk)
      qf[u][kk] = *(const short8*)(Q + (size_t)(b * 2048 + qb + u * 16 + c) *
                                           1024 + h * 64 + kk * 32 + g * 8);

  f32x4 po[2][4] = {};
  f32x4 lac[2] = {};
  float m[2] = {-1e30f, -1e30f};

  // prologue: stage tile 0 into buf 0 (each thread: 2x16B K + 2x16B V)
  const unsigned short* kpf = Kbase + (size_t)srow8 * 64 + scs;
  const unsigned short* vpf = Vbase + (size_t)srow8 * 2048 + scs;
  GLDS16(kpf, &Kl[0][0] + tid * 8);
  GLDS16(kpf + 2048, &Kl[0][0] + tid * 8 + 2048);
  GLDS16(vpf, &Vl[0][0] + tid * 8);
  GLDS16(vpf + 65536, &Vl[0][0] + tid * 8 + 2048);
  kpf += 4096;
  vpf += 64;
  int cur = 0;
  const int nit = 2 * qt + 2;

  for (int it = 0; it < nit; ++it) {
    __syncthreads();  // buf[cur] staged; prev reads of cur^1 done

    if (it < nit - 1) {  // prefetch next tile into cur^1
      unsigned short* kd = &Kl[cur ^ 1][0] + tid * 8;
      unsigned short* vd = &Vl[cur ^ 1][0] + tid * 8;
      GLDS16(kpf, kd);
      GLDS16(kpf + 2048, kd + 2048);
      GLDS16(vpf, vd);
      GLDS16(vpf + 65536, vd + 2048);
      kpf += 4096;
      vpf += 64;
    }

    const unsigned short* Kt = &Kl[cur][0];
    const unsigned short* Vc = &Vl[cur][0];
    const int kv0 = it * 64;

    // S^T = K Q^T for both subtiles; each kf read feeds 2 MFMAs
    f32x4 s[2][4] = {};
    __builtin_amdgcn_s_setprio(1);
#pragma unroll
    for (int kk = 0; kk < 2; ++kk) {
      const int col = (kk * 32 + g * 8) ^ swr;
#pragma unroll
      for (int f = 0; f < 4; ++f) {
        short8 kf = *(const short8*)(Kt + (f * 16 + c) * 64 + col);
        s[0][f] = __builtin_amdgcn_mfma_f32_16x16x32_bf16(kf, qf[0][kk],
                                                          s[0][f], 0, 0, 0);
        s[1][f] = __builtin_amdgcn_mfma_f32_16x16x32_bf16(kf, qf[1][kk],
                                                          s[1][f], 0, 0, 0);
      }
    }
    __builtin_amdgcn_s_setprio(0);

    float pm[2];
#pragma unroll
    for (int u = 0; u < 2; ++u) {
      if (kv0 + 63 > qb + u * 16) {  // mask needed (diagonal or beyond)
        const int qi = qb + u * 16 + c;
#pragma unroll
        for (int f = 0; f < 4; ++f)
#pragma unroll
          for (int r = 0; r < 4; ++r)
            if (kv0 + f * 16 + g * 4 + r > qi) s[u][f][r] = -1e30f;
      }
      // lane-local max over 16 kv values (max3-fusable tree)
      const float t0 = fmaxf(fmaxf(s[u][0][0], s[u][0][1]), s[u][0][2]);
      const float t1 = fmaxf(fmaxf(s[u][0][3], s[u][1][0]), s[u][1][1]);
      const float t2 = fmaxf(fmaxf(s[u][1][2], s[u][1][3]), s[u][2][0]);
      const float t3 = fmaxf(fmaxf(s[u][2][1], s[u][2][2]), s[u][2][3]);
      const float t4 = fmaxf(fmaxf(s[u][3][0], s[u][3][1]), s[u][3][2]);
      const float u0 = fmaxf(fmaxf(t0, t1), t2);
      const float u1 = fmaxf(fmaxf(t3, t4), s[u][3][3]);
      pm[u] = fmaxf(u0, u1);
    }

    // defer-max: rescale only when some row's max grew past THR=8 (log2)
    if (!__all(pm[0] <= m[0] + 8.0f && pm[1] <= m[1] + 8.0f)) {
#pragma unroll
      for (int u = 0; u < 2; ++u) {
        float pmu = fmaxf(pm[u], __shfl_xor(pm[u], 16, 64));
        pmu = fmaxf(pmu, __shfl_xor(pmu, 32, 64));    // full max for q=c
        const float mn = fmaxf(m[u], pmu);
        const float al = __builtin_amdgcn_exp2f(m[u] - mn);
        m[u] = mn;
#pragma unroll
        for (int r = 0; r < 4; ++r) {
          const float ar = __shfl(al, g * 4 + r, 64);  // alpha for row g*4+r
          lac[u][r] *= ar;
#pragma unroll
          for (int fd = 0; fd < 4; ++fd) po[u][fd][r] *= ar;
        }
      }
    }

    // P = exp2(S - m): v_perm RTZ pack, bounce [q][kv] through wave LDS
#pragma unroll
    for (int u = 0; u < 2; ++u) {
#pragma unroll
      for (int f = 0; f < 4; ++f) {
        const float p0 = __builtin_amdgcn_exp2f(s[u][f][0] - m[u]);
        const float p1 = __builtin_amdgcn_exp2f(s[u][f][1] - m[u]);
        const float p2 = __builtin_amdgcn_exp2f(s[u][f][2] - m[u]);
        const float p3 = __builtin_amdgcn_exp2f(s[u][f][3] - m[u]);
        uint2 pk;
        pk.x = pack_bf2_rtz(p0, p1);
        pk.y = pack_bf2_rtz(p2, p3);
        *(uint2*)(pd + (u * 16 + c) * 36 + f * 8 + g * 2) = pk;
      }
    }

    // O += P V ; l += P 1  (each vf read feeds 2 MFMAs)
    __builtin_amdgcn_s_setprio(1);
#pragma unroll
    for (int kk = 0; kk < 2; ++kk) {
      short8 pa0 = *(const short8*)(pw + c * 72 + kk * 32 + g * 8);
      short8 pa1 = *(const short8*)(pw + (16 + c) * 72 + kk * 32 + g * 8);
      lac[0] = __builtin_amdgcn_mfma_f32_16x16x32_bf16(pa0, ones, lac[0], 0, 0, 0);
      lac[1] = __builtin_amdgcn_mfma_f32_16x16x32_bf16(pa1, ones, lac[1], 0, 0, 0);
      const int col = (kk * 32 + g * 8) ^ swr;
#pragma unroll
      for (int fd = 0; fd < 4; ++fd) {
        short8 vf = *(const short8*)(Vc + (fd * 16 + c) * 64 + col);
        po[0][fd] = __builtin_amdgcn_mfma_f32_16x16x32_bf16(pa0, vf, po[0][fd],
                                                            0, 0, 0);
        po[1][fd] = __builtin_amdgcn_mfma_f32_16x16x32_bf16(pa1, vf, po[1][fd],
                                                            0, 0, 0);
      }
    }
    __builtin_amdgcn_s_setprio(0);
    cur ^= 1;
  }

  // epilogue: O / l
#pragma unroll
  for (int u = 0; u < 2; ++u) {
#pragma unroll
    for (int r = 0; r < 4; ++r) {
      const float inv = __builtin_amdgcn_rcpf(lac[u][r]);
      const int trow = qb + u * 16 + g * 4 + r;
#pragma unroll
      for (int fd = 0; fd < 4; ++fd)
        Oc[(size_t)(b * 2048 + trow) * 1024 + h * 64 + fd * 16 + c] =
            f2bf(po[u][fd][r] * inv);
    }
  }
}

// ---------- launch ----------
extern "C" void kernel_launch(void* const* d_in, const int* in_sizes, int n_in,
                              void* d_out, int out_size, void* d_ws,
                              size_t ws_size, hipStream_t stream) {
  const float* x = (const float*)d_in[0];
  const float* Wq = (const float*)d_in[1];
  const float* Wk = (const float*)d_in[2];
  const float* Wv = (const float*)d_in[3];
  const float* Wo = (const float*)d_in[4];
  float* out = (float*)d_out;

  char* ws = (char*)d_ws;
  unsigned short* xb   = (unsigned short*)ws;                          // 16 MB
  unsigned short* Qb   = (unsigned short*)(ws + (size_t)(16u << 20));  // 16 MB
  unsigned short* Attn = (unsigned short*)(ws + (size_t)(32u << 20));  // 16 MB
  unsigned short* Wcat = (unsigned short*)(ws + (size_t)(48u << 20));  // 2.25 MB
  unsigned short* Wot  = (unsigned short*)(ws + (size_t)(48u << 20) + 2359296);
  unsigned short* Kb   = (unsigned short*)(ws + (size_t)(48u << 20) + 2359296 + 2097152);
  unsigned short* Vtb  = (unsigned short*)(ws + (size_t)(48u << 20) + 2359296 + 2097152 + 1048576);
  unsigned short* Vrow = Attn;  // V staging row-major; dead before attn writes O

  // 1) cast x, fused weight transposes
  cast_x_bf16<<<8192, 256, 0, stream>>>((const float4*)x, (ushort4*)xb, 2097152);
  transpose_cvt_all<<<dim3(32, 32, 3), dim3(32, 8), 0, stream>>>(Wq, Wk, Wv, Wo,
                                                                 Wcat, Wot);

  // 2) fused QKV GEMM (V written coalesced), then V transpose
  gemm_bt<0><<<dim3(9, 64), 256, 0, stream>>>(xb, Wcat, Qb, Kb, Vrow, nullptr,
                                              1152, 1024);
  transpose_v<<<dim3(64, 2, 4), dim3(32, 8), 0, stream>>>(Vrow, Vtb);

  // 3) causal MQA flash attention (4-wave blocks, 3/CU + backfill queue)
  attn_mqa<<<1024, 256, 0, stream>>>(Qb, Kb, Vtb, Attn);

  // 4) output projection: [8192][1024] x [1024][1024]^T -> fp32 d_out
  gemm_bt<1><<<dim3(8, 64), 256, 0, stream>>>(Attn, Wot, nullptr, nullptr,
                                              nullptr, out, 1024, 1024);
}

// Round 17
// 146.861 us; speedup vs baseline: 1.8722x; 1.0001x over previous
//
#include <hip/hip_runtime.h>

typedef __attribute__((ext_vector_type(8))) short short8;
typedef __attribute__((ext_vector_type(4))) float f32x4;

// ---------- helpers ----------
__device__ __forceinline__ unsigned short f2bf(float f) {
  unsigned u = __builtin_bit_cast(unsigned, f);
  u += 0x7fffu + ((u >> 16) & 1u);   // RNE
  return (unsigned short)(u >> 16);
}
// pack two f32 -> two bf16 (RTZ) in ONE v_perm_b32: bytes [p1.hi16 : p0.hi16]
__device__ __forceinline__ unsigned pack_bf2_rtz(float p0, float p1) {
  return __builtin_amdgcn_perm(__builtin_bit_cast(unsigned, p1),
                               __builtin_bit_cast(unsigned, p0), 0x07060302u);
}

#define GLDS16(g, l)                                                          \
  __builtin_amdgcn_global_load_lds(                                           \
      (const __attribute__((address_space(1))) void*)(g),                     \
      (__attribute__((address_space(3))) void*)(l), 16, 0, 0)

// Q pre-scale: HEAD_DIM^-0.5 * log2(e), so softmax uses exp2 directly.
#define QSCALE 0.18033688011112042f

// ---------- cast x (fp32 -> bf16), vectorized ----------
__global__ void cast_x_bf16(const float4* __restrict__ in,
                            ushort4* __restrict__ out, int n4) {
  int i = blockIdx.x * blockDim.x + threadIdx.x;
  if (i >= n4) return;
  float4 v = in[i];
  ushort4 o;
  o.x = f2bf(v.x); o.y = f2bf(v.y); o.z = f2bf(v.z); o.w = f2bf(v.w);
  out[i] = o;
}

// ---------- fused transpose+convert of all weights (one launch) ----------
__global__ void transpose_cvt_all(const float* __restrict__ Wq,
                                  const float* __restrict__ Wk,
                                  const float* __restrict__ Wv,
                                  const float* __restrict__ Wo,
                                  unsigned short* __restrict__ Wcat,
                                  unsigned short* __restrict__ Wot) {
  __shared__ float tile[32][33];
  const int z = blockIdx.z;
  int bx = blockIdx.x;
  const float* in;
  unsigned short* out;
  int N;
  if (z == 0)      { in = Wq; out = Wcat;               N = 1024; }
  else if (z == 1) { in = Wo; out = Wot;                N = 1024; }
  else {
    if (bx < 2)      { in = Wk; out = Wcat + 1024 * 1024; N = 64; }
    else if (bx < 4) { in = Wv; out = Wcat + 1088 * 1024; N = 64; bx -= 2; }
    else return;
  }
  const int K = 1024;
  const int n0 = bx * 32, k0 = blockIdx.y * 32;
  const int tx = threadIdx.x, ty = threadIdx.y;  // block (32,8)
#pragma unroll
  for (int i = 0; i < 4; ++i)
    tile[ty + 8 * i][tx] = in[(size_t)(k0 + ty + 8 * i) * N + n0 + tx];
  __syncthreads();
#pragma unroll
  for (int i = 0; i < 4; ++i)
    out[(size_t)(n0 + ty + 8 * i) * K + k0 + tx] = f2bf(tile[tx][ty + 8 * i]);
}

// ---------- transpose V: Vr [b*2048+t][64] -> Vt [b][64][2048] ----------
__global__ void transpose_v(const unsigned short* __restrict__ Vr,
                            unsigned short* __restrict__ Vt) {
  __shared__ unsigned short tile[32][34];
  const int t0 = blockIdx.x * 32;
  const int d0 = blockIdx.y * 32;
  const int b = blockIdx.z;
  const int tx = threadIdx.x, ty = threadIdx.y;  // block (32,8)
#pragma unroll
  for (int i = 0; i < 4; ++i)
    tile[ty + 8 * i][tx] =
        Vr[(size_t)(b * 2048 + t0 + ty + 8 * i) * 64 + d0 + tx];
  __syncthreads();
#pragma unroll
  for (int i = 0; i < 4; ++i)
    Vt[((size_t)b * 64 + d0 + ty + 8 * i) * 2048 + t0 + tx] =
        tile[tx][ty + 8 * i];
}

// ---------- GEMM: C[M][N] = A[M][K](bf16) * Bt[N][K](bf16)^T ----------
// m97 structure + bijective XCD-aware block swizzle (grid %8 == 0).
template <int EPI>
__global__ __launch_bounds__(256) void gemm_bt(
    const unsigned short* __restrict__ A, const unsigned short* __restrict__ Bt,
    unsigned short* __restrict__ Cq, unsigned short* __restrict__ Ck,
    unsigned short* __restrict__ Cv, float* __restrict__ Cf, int N, int K) {
  __shared__ __align__(16) unsigned short As[128 * 64];
  __shared__ __align__(16) unsigned short Bs[128 * 64];
  const int tid = threadIdx.x;
  const int w = tid >> 6, lane = tid & 63;
  const int nwg = gridDim.x * gridDim.y;
  const int lid = blockIdx.y * gridDim.x + blockIdx.x;
  const int cpx = nwg >> 3;
  const int swz = (lid & 7) * cpx + (lid >> 3);
  const int m0 = (swz / gridDim.x) * 128, n0 = (swz % gridDim.x) * 128;
  const int wm = (w >> 1) * 64, wn = (w & 1) * 64;
  const int g = lane >> 4, c = lane & 15;
  const int lr = lane >> 3, lc = (lane & 7) * 8;

  f32x4 acc[4][4] = {};

  for (int k0 = 0; k0 < K; k0 += 64) {
#pragma unroll
    for (int i = 0; i < 4; ++i) {
      int ci = w * 4 + i;  // 1KB chunk: rows 8ci..8ci+7
      GLDS16(A + (size_t)(m0 + ci * 8 + lr) * K + k0 + lc, As + ci * 512);
      GLDS16(Bt + (size_t)(n0 + ci * 8 + lr) * K + k0 + lc, Bs + ci * 512);
    }
    __syncthreads();
#pragma unroll
    for (int kk = 0; kk < 2; ++kk) {
      const int col = kk * 32 + g * 8;
      short8 av[4], bv[4];
#pragma unroll
      for (int mi = 0; mi < 4; ++mi)
        av[mi] = *(const short8*)(As + (wm + mi * 16 + c) * 64 + col);
#pragma unroll
      for (int ni = 0; ni < 4; ++ni)
        bv[ni] = *(const short8*)(Bs + (wn + ni * 16 + c) * 64 + col);
#pragma unroll
      for (int mi = 0; mi < 4; ++mi)
#pragma unroll
        for (int ni = 0; ni < 4; ++ni)
          acc[mi][ni] = __builtin_amdgcn_mfma_f32_16x16x32_bf16(
              av[mi], bv[ni], acc[mi][ni], 0, 0, 0);
    }
    __syncthreads();
  }

#pragma unroll
  for (int mi = 0; mi < 4; ++mi) {
#pragma unroll
    for (int ni = 0; ni < 4; ++ni) {
      f32x4 a = acc[mi][ni];
      const int col = n0 + wn + ni * 16 + c;
#pragma unroll
      for (int r = 0; r < 4; ++r) {
        const int row = m0 + wm + mi * 16 + g * 4 + r;
        float v = a[r];
        if (EPI == 0) {
          if (col < 1024)
            Cq[(size_t)row * 1024 + col] = f2bf(v * QSCALE);
          else if (col < 1088)
            Ck[(size_t)row * 64 + (col - 1024)] = f2bf(v);
          else  // V coalesced [row][64]; transposed by transpose_v
            Cv[(size_t)row * 64 + (col - 1088)] = f2bf(v);
        } else {
          Cf[(size_t)row * N + col] = v;
        }
      }
    }
  }
}

// ---------- causal multi-query flash attention, v8 (best-known, R9) ----------
// 256-thr blocks: 4 waves = 1 head x 4 q-waves, each wave q=32 (two 16-row
// subtiles). K+V double-buffered in LDS via global_load_lds (51.2 KB ->
// 3 blocks/CU); grid 1024 -> 256 blocks queue and BACKFILL as short blocks
// finish; longest blocks dispatch first. Swapped QK^T lane-local softmax;
// defer-max THR=8; l via ones-MFMA; P-pack v_perm RTZ.
// [R10: KVBLK=32 + 6-block bound -> VGPR spill, 2.7x worse. R14/R15:
//  V-direct-from-global -> scattered 16B/lane reads thrash L1, FETCH 5x,
//  latency-bound collapse. Batch-staged K+V behind 1 barrier/iter is the
//  proven optimum for this op.]
__global__ __launch_bounds__(256, 3) void attn_mqa(
    const unsigned short* __restrict__ Q, const unsigned short* __restrict__ Kb,
    const unsigned short* __restrict__ Vt, unsigned short* __restrict__ Oc) {
  __shared__ __align__(16) unsigned short Kl[2][64 * 64];
  __shared__ __align__(16) unsigned short Vl[2][64 * 64];
  __shared__ __align__(16) unsigned short Pl[4][32 * 72];
  const int tid = threadIdx.x;
  const int w = tid >> 6, lane = tid & 63;
  const int bid = blockIdx.x;            // 0..1023
  const int b = bid & 3;
  const int h = (bid >> 2) & 15;
  const int qidx = (bid >> 6) & 15;
  const int qt = 15 - qidx;              // long blocks first in dispatch order
  const int g = lane >> 4, c = lane & 15;
  const int swr = (c & 7) * 8;            // read-side xor (shorts)
  const int srow8 = tid >> 3;             // staging row 0..31 (pass adds 32)
  const int scs = ((tid & 7) ^ (srow8 & 7)) * 8;  // swizzled source col
  const unsigned short* Kbase = Kb + (size_t)b * 2048 * 64;
  const unsigned short* Vbase = Vt + (size_t)b * 64 * 2048;
  unsigned short* pw = Pl[w];
  unsigned* pd = (unsigned*)pw;           // dword view, row stride 36

  short8 ones;
#pragma unroll
  for (int j = 0; j < 8; ++j) ones[j] = (short)0x3F80;  // bf16 1.0

  const int qb = qt * 128 + w * 32;       // wave's first q row

  // Q fragments (B-operand: col=c, k=g*8+j) for both subtiles, pre-scaled
  short8 qf[2][2];
#pragma unroll
  for (int u = 0; u < 2; ++u)
#pragma unroll
    for (int kk = 0; kk < 2; ++kk)
      qf[u][kk] = *(const short8*)(Q + (size_t)(b * 2048 + qb + u * 16 + c) *
                                           1024 + h * 64 + kk * 32 + g * 8);

  f32x4 po[2][4] = {};
  f32x4 lac[2] = {};
  float m[2] = {-1e30f, -1e30f};

  // prologue: stage tile 0 into buf 0 (each thread: 2x16B K + 2x16B V)
  const unsigned short* kpf = Kbase + (size_t)srow8 * 64 + scs;
  const unsigned short* vpf = Vbase + (size_t)srow8 * 2048 + scs;
  GLDS16(kpf, &Kl[0][0] + tid * 8);
  GLDS16(kpf + 2048, &Kl[0][0] + tid * 8 + 2048);
  GLDS16(vpf, &Vl[0][0] + tid * 8);
  GLDS16(vpf + 65536, &Vl[0][0] + tid * 8 + 2048);
  kpf += 4096;
  vpf += 64;
  int cur = 0;
  const int nit = 2 * qt + 2;

  for (int it = 0; it < nit; ++it) {
    __syncthreads();  // buf[cur] staged; prev reads of cur^1 done

    if (it < nit - 1) {  // prefetch next tile into cur^1
      unsigned short* kd = &Kl[cur ^ 1][0] + tid * 8;
      unsigned short* vd = &Vl[cur ^ 1][0] + tid * 8;
      GLDS16(kpf, kd);
      GLDS16(kpf + 2048, kd + 2048);
      GLDS16(vpf, vd);
      GLDS16(vpf + 65536, vd + 2048);
      kpf += 4096;
      vpf += 64;
    }

    const unsigned short* Kt = &Kl[cur][0];
    const unsigned short* Vc = &Vl[cur][0];
    const int kv0 = it * 64;

    // S^T = K Q^T for both subtiles; each kf read feeds 2 MFMAs
    f32x4 s[2][4] = {};
    __builtin_amdgcn_s_setprio(1);
#pragma unroll
    for (int kk = 0; kk < 2; ++kk) {
      const int col = (kk * 32 + g * 8) ^ swr;
#pragma unroll
      for (int f = 0; f < 4; ++f) {
        short8 kf = *(const short8*)(Kt + (f * 16 + c) * 64 + col);
        s[0][f] = __builtin_amdgcn_mfma_f32_16x16x32_bf16(kf, qf[0][kk],
                                                          s[0][f], 0, 0, 0);
        s[1][f] = __builtin_amdgcn_mfma_f32_16x16x32_bf16(kf, qf[1][kk],
                                                          s[1][f], 0, 0, 0);
      }
    }
    __builtin_amdgcn_s_setprio(0);

    float pm[2];
#pragma unroll
    for (int u = 0; u < 2; ++u) {
      if (kv0 + 63 > qb + u * 16) {  // mask needed (diagonal or beyond)
        const int qi = qb + u * 16 + c;
#pragma unroll
        for (int f = 0; f < 4; ++f)
#pragma unroll
          for (int r = 0; r < 4; ++r)
            if (kv0 + f * 16 + g * 4 + r > qi) s[u][f][r] = -1e30f;
      }
      // lane-local max over 16 kv values (max3-fusable tree)
      const float t0 = fmaxf(fmaxf(s[u][0][0], s[u][0][1]), s[u][0][2]);
      const float t1 = fmaxf(fmaxf(s[u][0][3], s[u][1][0]), s[u][1][1]);
      const float t2 = fmaxf(fmaxf(s[u][1][2], s[u][1][3]), s[u][2][0]);
      const float t3 = fmaxf(fmaxf(s[u][2][1], s[u][2][2]), s[u][2][3]);
      const float t4 = fmaxf(fmaxf(s[u][3][0], s[u][3][1]), s[u][3][2]);
      const float u0 = fmaxf(fmaxf(t0, t1), t2);
      const float u1 = fmaxf(fmaxf(t3, t4), s[u][3][3]);
      pm[u] = fmaxf(u0, u1);
    }

    // defer-max: rescale only when some row's max grew past THR=8 (log2)
    if (!__all(pm[0] <= m[0] + 8.0f && pm[1] <= m[1] + 8.0f)) {
#pragma unroll
      for (int u = 0; u < 2; ++u) {
        float pmu = fmaxf(pm[u], __shfl_xor(pm[u], 16, 64));
        pmu = fmaxf(pmu, __shfl_xor(pmu, 32, 64));    // full max for q=c
        const float mn = fmaxf(m[u], pmu);
        const float al = __builtin_amdgcn_exp2f(m[u] - mn);
        m[u] = mn;
#pragma unroll
        for (int r = 0; r < 4; ++r) {
          const float ar = __shfl(al, g * 4 + r, 64);  // alpha for row g*4+r
          lac[u][r] *= ar;
#pragma unroll
          for (int fd = 0; fd < 4; ++fd) po[u][fd][r] *= ar;
        }
      }
    }

    // P = exp2(S - m): v_perm RTZ pack, bounce [q][kv] through wave LDS
#pragma unroll
    for (int u = 0; u < 2; ++u) {
#pragma unroll
      for (int f = 0; f < 4; ++f) {
        const float p0 = __builtin_amdgcn_exp2f(s[u][f][0] - m[u]);
        const float p1 = __builtin_amdgcn_exp2f(s[u][f][1] - m[u]);
        const float p2 = __builtin_amdgcn_exp2f(s[u][f][2] - m[u]);
        const float p3 = __builtin_amdgcn_exp2f(s[u][f][3] - m[u]);
        uint2 pk;
        pk.x = pack_bf2_rtz(p0, p1);
        pk.y = pack_bf2_rtz(p2, p3);
        *(uint2*)(pd + (u * 16 + c) * 36 + f * 8 + g * 2) = pk;
      }
    }

    // O += P V ; l += P 1  (each vf read feeds 2 MFMAs)
    __builtin_amdgcn_s_setprio(1);
#pragma unroll
    for (int kk = 0; kk < 2; ++kk) {
      short8 pa0 = *(const short8*)(pw + c * 72 + kk * 32 + g * 8);
      short8 pa1 = *(const short8*)(pw + (16 + c) * 72 + kk * 32 + g * 8);
      lac[0] = __builtin_amdgcn_mfma_f32_16x16x32_bf16(pa0, ones, lac[0], 0, 0, 0);
      lac[1] = __builtin_amdgcn_mfma_f32_16x16x32_bf16(pa1, ones, lac[1], 0, 0, 0);
      const int col = (kk * 32 + g * 8) ^ swr;
#pragma unroll
      for (int fd = 0; fd < 4; ++fd) {
        short8 vf = *(const short8*)(Vc + (fd * 16 + c) * 64 + col);
        po[0][fd] = __builtin_amdgcn_mfma_f32_16x16x32_bf16(pa0, vf, po[0][fd],
                                                            0, 0, 0);
        po[1][fd] = __builtin_amdgcn_mfma_f32_16x16x32_bf16(pa1, vf, po[1][fd],
                                                            0, 0, 0);
      }
    }
    __builtin_amdgcn_s_setprio(0);
    cur ^= 1;
  }

  // epilogue: O / l
#pragma unroll
  for (int u = 0; u < 2; ++u) {
#pragma unroll
    for (int r = 0; r < 4; ++r) {
      const float inv = __builtin_amdgcn_rcpf(lac[u][r]);
      const int trow = qb + u * 16 + g * 4 + r;
#pragma unroll
      for (int fd = 0; fd < 4; ++fd)
        Oc[(size_t)(b * 2048 + trow) * 1024 + h * 64 + fd * 16 + c] =
            f2bf(po[u][fd][r] * inv);
    }
  }
}

// ---------- launch ----------
extern "C" void kernel_launch(void* const* d_in, const int* in_sizes, int n_in,
                              void* d_out, int out_size, void* d_ws,
                              size_t ws_size, hipStream_t stream) {
  const float* x = (const float*)d_in[0];
  const float* Wq = (const float*)d_in[1];
  const float* Wk = (const float*)d_in[2];
  const float* Wv = (const float*)d_in[3];
  const float* Wo = (const float*)d_in[4];
  float* out = (float*)d_out;

  char* ws = (char*)d_ws;
  unsigned short* xb   = (unsigned short*)ws;                          // 16 MB
  unsigned short* Qb   = (unsigned short*)(ws + (size_t)(16u << 20));  // 16 MB
  unsigned short* Attn = (unsigned short*)(ws + (size_t)(32u << 20));  // 16 MB
  unsigned short* Wcat = (unsigned short*)(ws + (size_t)(48u << 20));  // 2.25 MB
  unsigned short* Wot  = (unsigned short*)(ws + (size_t)(48u << 20) + 2359296);
  unsigned short* Kb   = (unsigned short*)(ws + (size_t)(48u << 20) + 2359296 + 2097152);
  unsigned short* Vtb  = (unsigned short*)(ws + (size_t)(48u << 20) + 2359296 + 2097152 + 1048576);
  unsigned short* Vrow = Attn;  // V staging row-major; dead before attn writes O

  // 1) cast x, fused weight transposes
  cast_x_bf16<<<8192, 256, 0, stream>>>((const float4*)x, (ushort4*)xb, 2097152);
  transpose_cvt_all<<<dim3(32, 32, 3), dim3(32, 8), 0, stream>>>(Wq, Wk, Wv, Wo,
                                                                 Wcat, Wot);

  // 2) fused QKV GEMM (V written coalesced), then V transpose
  gemm_bt<0><<<dim3(9, 64), 256, 0, stream>>>(xb, Wcat, Qb, Kb, Vrow, nullptr,
                                              1152, 1024);
  transpose_v<<<dim3(64, 2, 4), dim3(32, 8), 0, stream>>>(Vrow, Vtb);

  // 3) causal MQA flash attention (4-wave blocks, 3/CU + backfill queue)
  attn_mqa<<<1024, 256, 0, stream>>>(Qb, Kb, Vtb, Attn);

  // 4) output projection: [8192][1024] x [1024][1024]^T -> fp32 d_out
  gemm_bt<1><<<dim3(8, 64), 256, 0, stream>>>(Attn, Wot, nullptr, nullptr,
                                              nullptr, out, 1024, 1024);
}

// Round 18
// 144.201 us; speedup vs baseline: 1.9067x; 1.0184x over previous
//
#include <hip/hip_runtime.h>

typedef __attribute__((ext_vector_type(8))) short short8;
typedef __attribute__((ext_vector_type(4))) float f32x4;

// ---------- helpers ----------
__device__ __forceinline__ unsigned short f2bf(float f) {
  unsigned u = __builtin_bit_cast(unsigned, f);
  u += 0x7fffu + ((u >> 16) & 1u);   // RNE
  return (unsigned short)(u >> 16);
}
// pack two f32 -> two bf16 (RTZ) in ONE v_perm_b32: bytes [p1.hi16 : p0.hi16]
__device__ __forceinline__ unsigned pack_bf2_rtz(float p0, float p1) {
  return __builtin_amdgcn_perm(__builtin_bit_cast(unsigned, p1),
                               __builtin_bit_cast(unsigned, p0), 0x07060302u);
}

#define GLDS16(g, l)                                                          \
  __builtin_amdgcn_global_load_lds(                                           \
      (const __attribute__((address_space(1))) void*)(g),                     \
      (__attribute__((address_space(3))) void*)(l), 16, 0, 0)

// Q pre-scale: HEAD_DIM^-0.5 * log2(e), so softmax uses exp2 directly.
#define QSCALE 0.18033688011112042f

// ---------- fused prep: weight transposes (z=0..2) + x cast (z=3) ----------
// One launch replaces cast_x_bf16 + transpose_cvt_all.
__global__ void prep_all(const float* __restrict__ x,
                         const float* __restrict__ Wq,
                         const float* __restrict__ Wk,
                         const float* __restrict__ Wv,
                         const float* __restrict__ Wo,
                         ushort4* __restrict__ xb,
                         unsigned short* __restrict__ Wcat,
                         unsigned short* __restrict__ Wot) {
  const int z = blockIdx.z;
  if (z == 3) {  // cast x: 8M float4 over 1024 blocks x 256 thr x 8 iters
    const int base = (blockIdx.y * 32 + blockIdx.x) * 256 +
                     threadIdx.y * 32 + threadIdx.x;
    const float4* in4 = (const float4*)x;
#pragma unroll
    for (int i = 0; i < 8; ++i) {
      const int idx = base + i * 262144;
      float4 v = in4[idx];
      ushort4 o;
      o.x = f2bf(v.x); o.y = f2bf(v.y); o.z = f2bf(v.z); o.w = f2bf(v.w);
      xb[idx] = o;
    }
    return;
  }
  __shared__ float tile[32][33];
  int bx = blockIdx.x;
  const float* in;
  unsigned short* out;
  int N;
  if (z == 0)      { in = Wq; out = Wcat;               N = 1024; }
  else if (z == 1) { in = Wo; out = Wot;                N = 1024; }
  else {
    if (bx < 2)      { in = Wk; out = Wcat + 1024 * 1024; N = 64; }
    else if (bx < 4) { in = Wv; out = Wcat + 1088 * 1024; N = 64; bx -= 2; }
    else return;
  }
  const int K = 1024;
  const int n0 = bx * 32, k0 = blockIdx.y * 32;
  const int tx = threadIdx.x, ty = threadIdx.y;  // block (32,8)
#pragma unroll
  for (int i = 0; i < 4; ++i)
    tile[ty + 8 * i][tx] = in[(size_t)(k0 + ty + 8 * i) * N + n0 + tx];
  __syncthreads();
#pragma unroll
  for (int i = 0; i < 4; ++i)
    out[(size_t)(n0 + ty + 8 * i) * K + k0 + tx] = f2bf(tile[tx][ty + 8 * i]);
}

// ---------- GEMM: C[M][N] = A[M][K](bf16) * Bt[N][K](bf16)^T ----------
// m97 structure + bijective XCD-aware block swizzle (grid %8 == 0).
// EPI==0: QKV epilogue (col<1024 -> Q*QSCALE; col<1088 -> K [row][64];
//         else V scattered directly into Vt [b][d][t] — proven R1-R6).
// EPI==1: plain fp32 C.
template <int EPI>
__global__ __launch_bounds__(256) void gemm_bt(
    const unsigned short* __restrict__ A, const unsigned short* __restrict__ Bt,
    unsigned short* __restrict__ Cq, unsigned short* __restrict__ Ck,
    unsigned short* __restrict__ Cv, float* __restrict__ Cf, int N, int K) {
  __shared__ __align__(16) unsigned short As[128 * 64];
  __shared__ __align__(16) unsigned short Bs[128 * 64];
  const int tid = threadIdx.x;
  const int w = tid >> 6, lane = tid & 63;
  const int nwg = gridDim.x * gridDim.y;
  const int lid = blockIdx.y * gridDim.x + blockIdx.x;
  const int cpx = nwg >> 3;
  const int swz = (lid & 7) * cpx + (lid >> 3);
  const int m0 = (swz / gridDim.x) * 128, n0 = (swz % gridDim.x) * 128;
  const int wm = (w >> 1) * 64, wn = (w & 1) * 64;
  const int g = lane >> 4, c = lane & 15;
  const int lr = lane >> 3, lc = (lane & 7) * 8;

  f32x4 acc[4][4] = {};

  for (int k0 = 0; k0 < K; k0 += 64) {
#pragma unroll
    for (int i = 0; i < 4; ++i) {
      int ci = w * 4 + i;  // 1KB chunk: rows 8ci..8ci+7
      GLDS16(A + (size_t)(m0 + ci * 8 + lr) * K + k0 + lc, As + ci * 512);
      GLDS16(Bt + (size_t)(n0 + ci * 8 + lr) * K + k0 + lc, Bs + ci * 512);
    }
    __syncthreads();
#pragma unroll
    for (int kk = 0; kk < 2; ++kk) {
      const int col = kk * 32 + g * 8;
      short8 av[4], bv[4];
#pragma unroll
      for (int mi = 0; mi < 4; ++mi)
        av[mi] = *(const short8*)(As + (wm + mi * 16 + c) * 64 + col);
#pragma unroll
      for (int ni = 0; ni < 4; ++ni)
        bv[ni] = *(const short8*)(Bs + (wn + ni * 16 + c) * 64 + col);
#pragma unroll
      for (int mi = 0; mi < 4; ++mi)
#pragma unroll
        for (int ni = 0; ni < 4; ++ni)
          acc[mi][ni] = __builtin_amdgcn_mfma_f32_16x16x32_bf16(
              av[mi], bv[ni], acc[mi][ni], 0, 0, 0);
    }
    __syncthreads();
  }

#pragma unroll
  for (int mi = 0; mi < 4; ++mi) {
#pragma unroll
    for (int ni = 0; ni < 4; ++ni) {
      f32x4 a = acc[mi][ni];
      const int col = n0 + wn + ni * 16 + c;
#pragma unroll
      for (int r = 0; r < 4; ++r) {
        const int row = m0 + wm + mi * 16 + g * 4 + r;
        float v = a[r];
        if (EPI == 0) {
          if (col < 1024)
            Cq[(size_t)row * 1024 + col] = f2bf(v * QSCALE);
          else if (col < 1088)
            Ck[(size_t)row * 64 + (col - 1024)] = f2bf(v);
          else  // V scattered directly into Vt [b][d][t]
            Cv[((size_t)(row >> 11) * 64 + (col - 1088)) * 2048 + (row & 2047)] =
                f2bf(v);
        } else {
          Cf[(size_t)row * N + col] = v;
        }
      }
    }
  }
}

// ---------- causal multi-query flash attention, v8 (best-known, R9) ----------
// 256-thr blocks: 4 waves = 1 head x 4 q-waves, each wave q=32 (two 16-row
// subtiles). K+V double-buffered in LDS via global_load_lds (51.2 KB ->
// 3 blocks/CU); grid 1024 -> 256 blocks queue and BACKFILL as short blocks
// finish; longest blocks dispatch first. Swapped QK^T lane-local softmax;
// defer-max THR=8; l via ones-MFMA; P-pack v_perm RTZ.
// [R10: KVBLK=32 + 6-block bound -> VGPR spill, 2.7x worse. R14/R15:
//  V-direct-from-global -> scattered 16B/lane reads thrash L1, FETCH 5x,
//  latency-bound collapse. Batch-staged K+V behind 1 barrier/iter is the
//  proven optimum for this op.]
__global__ __launch_bounds__(256, 3) void attn_mqa(
    const unsigned short* __restrict__ Q, const unsigned short* __restrict__ Kb,
    const unsigned short* __restrict__ Vt, unsigned short* __restrict__ Oc) {
  __shared__ __align__(16) unsigned short Kl[2][64 * 64];
  __shared__ __align__(16) unsigned short Vl[2][64 * 64];
  __shared__ __align__(16) unsigned short Pl[4][32 * 72];
  const int tid = threadIdx.x;
  const int w = tid >> 6, lane = tid & 63;
  const int bid = blockIdx.x;            // 0..1023
  const int b = bid & 3;
  const int h = (bid >> 2) & 15;
  const int qidx = (bid >> 6) & 15;
  const int qt = 15 - qidx;              // long blocks first in dispatch order
  const int g = lane >> 4, c = lane & 15;
  const int swr = (c & 7) * 8;            // read-side xor (shorts)
  const int srow8 = tid >> 3;             // staging row 0..31 (pass adds 32)
  const int scs = ((tid & 7) ^ (srow8 & 7)) * 8;  // swizzled source col
  const unsigned short* Kbase = Kb + (size_t)b * 2048 * 64;
  const unsigned short* Vbase = Vt + (size_t)b * 64 * 2048;
  unsigned short* pw = Pl[w];
  unsigned* pd = (unsigned*)pw;           // dword view, row stride 36

  short8 ones;
#pragma unroll
  for (int j = 0; j < 8; ++j) ones[j] = (short)0x3F80;  // bf16 1.0

  const int qb = qt * 128 + w * 32;       // wave's first q row

  // Q fragments (B-operand: col=c, k=g*8+j) for both subtiles, pre-scaled
  short8 qf[2][2];
#pragma unroll
  for (int u = 0; u < 2; ++u)
#pragma unroll
    for (int kk = 0; kk < 2; ++kk)
      qf[u][kk] = *(const short8*)(Q + (size_t)(b * 2048 + qb + u * 16 + c) *
                                           1024 + h * 64 + kk * 32 + g * 8);

  f32x4 po[2][4] = {};
  f32x4 lac[2] = {};
  float m[2] = {-1e30f, -1e30f};

  // prologue: stage tile 0 into buf 0 (each thread: 2x16B K + 2x16B V)
  const unsigned short* kpf = Kbase + (size_t)srow8 * 64 + scs;
  const unsigned short* vpf = Vbase + (size_t)srow8 * 2048 + scs;
  GLDS16(kpf, &Kl[0][0] + tid * 8);
  GLDS16(kpf + 2048, &Kl[0][0] + tid * 8 + 2048);
  GLDS16(vpf, &Vl[0][0] + tid * 8);
  GLDS16(vpf + 65536, &Vl[0][0] + tid * 8 + 2048);
  kpf += 4096;
  vpf += 64;
  int cur = 0;
  const int nit = 2 * qt + 2;

  for (int it = 0; it < nit; ++it) {
    __syncthreads();  // buf[cur] staged; prev reads of cur^1 done

    if (it < nit - 1) {  // prefetch next tile into cur^1
      unsigned short* kd = &Kl[cur ^ 1][0] + tid * 8;
      unsigned short* vd = &Vl[cur ^ 1][0] + tid * 8;
      GLDS16(kpf, kd);
      GLDS16(kpf + 2048, kd + 2048);
      GLDS16(vpf, vd);
      GLDS16(vpf + 65536, vd + 2048);
      kpf += 4096;
      vpf += 64;
    }

    const unsigned short* Kt = &Kl[cur][0];
    const unsigned short* Vc = &Vl[cur][0];
    const int kv0 = it * 64;

    // S^T = K Q^T for both subtiles; each kf read feeds 2 MFMAs
    f32x4 s[2][4] = {};
    __builtin_amdgcn_s_setprio(1);
#pragma unroll
    for (int kk = 0; kk < 2; ++kk) {
      const int col = (kk * 32 + g * 8) ^ swr;
#pragma unroll
      for (int f = 0; f < 4; ++f) {
        short8 kf = *(const short8*)(Kt + (f * 16 + c) * 64 + col);
        s[0][f] = __builtin_amdgcn_mfma_f32_16x16x32_bf16(kf, qf[0][kk],
                                                          s[0][f], 0, 0, 0);
        s[1][f] = __builtin_amdgcn_mfma_f32_16x16x32_bf16(kf, qf[1][kk],
                                                          s[1][f], 0, 0, 0);
      }
    }
    __builtin_amdgcn_s_setprio(0);

    float pm[2];
#pragma unroll
    for (int u = 0; u < 2; ++u) {
      if (kv0 + 63 > qb + u * 16) {  // mask needed (diagonal or beyond)
        const int qi = qb + u * 16 + c;
#pragma unroll
        for (int f = 0; f < 4; ++f)
#pragma unroll
          for (int r = 0; r < 4; ++r)
            if (kv0 + f * 16 + g * 4 + r > qi) s[u][f][r] = -1e30f;
      }
      // lane-local max over 16 kv values (max3-fusable tree)
      const float t0 = fmaxf(fmaxf(s[u][0][0], s[u][0][1]), s[u][0][2]);
      const float t1 = fmaxf(fmaxf(s[u][0][3], s[u][1][0]), s[u][1][1]);
      const float t2 = fmaxf(fmaxf(s[u][1][2], s[u][1][3]), s[u][2][0]);
      const float t3 = fmaxf(fmaxf(s[u][2][1], s[u][2][2]), s[u][2][3]);
      const float t4 = fmaxf(fmaxf(s[u][3][0], s[u][3][1]), s[u][3][2]);
      const float u0 = fmaxf(fmaxf(t0, t1), t2);
      const float u1 = fmaxf(fmaxf(t3, t4), s[u][3][3]);
      pm[u] = fmaxf(u0, u1);
    }

    // defer-max: rescale only when some row's max grew past THR=8 (log2)
    if (!__all(pm[0] <= m[0] + 8.0f && pm[1] <= m[1] + 8.0f)) {
#pragma unroll
      for (int u = 0; u < 2; ++u) {
        float pmu = fmaxf(pm[u], __shfl_xor(pm[u], 16, 64));
        pmu = fmaxf(pmu, __shfl_xor(pmu, 32, 64));    // full max for q=c
        const float mn = fmaxf(m[u], pmu);
        const float al = __builtin_amdgcn_exp2f(m[u] - mn);
        m[u] = mn;
#pragma unroll
        for (int r = 0; r < 4; ++r) {
          const float ar = __shfl(al, g * 4 + r, 64);  // alpha for row g*4+r
          lac[u][r] *= ar;
#pragma unroll
          for (int fd = 0; fd < 4; ++fd) po[u][fd][r] *= ar;
        }
      }
    }

    // P = exp2(S - m): v_perm RTZ pack, bounce [q][kv] through wave LDS
#pragma unroll
    for (int u = 0; u < 2; ++u) {
#pragma unroll
      for (int f = 0; f < 4; ++f) {
        const float p0 = __builtin_amdgcn_exp2f(s[u][f][0] - m[u]);
        const float p1 = __builtin_amdgcn_exp2f(s[u][f][1] - m[u]);
        const float p2 = __builtin_amdgcn_exp2f(s[u][f][2] - m[u]);
        const float p3 = __builtin_amdgcn_exp2f(s[u][f][3] - m[u]);
        uint2 pk;
        pk.x = pack_bf2_rtz(p0, p1);
        pk.y = pack_bf2_rtz(p2, p3);
        *(uint2*)(pd + (u * 16 + c) * 36 + f * 8 + g * 2) = pk;
      }
    }

    // O += P V ; l += P 1  (each vf read feeds 2 MFMAs)
    __builtin_amdgcn_s_setprio(1);
#pragma unroll
    for (int kk = 0; kk < 2; ++kk) {
      short8 pa0 = *(const short8*)(pw + c * 72 + kk * 32 + g * 8);
      short8 pa1 = *(const short8*)(pw + (16 + c) * 72 + kk * 32 + g * 8);
      lac[0] = __builtin_amdgcn_mfma_f32_16x16x32_bf16(pa0, ones, lac[0], 0, 0, 0);
      lac[1] = __builtin_amdgcn_mfma_f32_16x16x32_bf16(pa1, ones, lac[1], 0, 0, 0);
      const int col = (kk * 32 + g * 8) ^ swr;
#pragma unroll
      for (int fd = 0; fd < 4; ++fd) {
        short8 vf = *(const short8*)(Vc + (fd * 16 + c) * 64 + col);
        po[0][fd] = __builtin_amdgcn_mfma_f32_16x16x32_bf16(pa0, vf, po[0][fd],
                                                            0, 0, 0);
        po[1][fd] = __builtin_amdgcn_mfma_f32_16x16x32_bf16(pa1, vf, po[1][fd],
                                                            0, 0, 0);
      }
    }
    __builtin_amdgcn_s_setprio(0);
    cur ^= 1;
  }

  // epilogue: O / l
#pragma unroll
  for (int u = 0; u < 2; ++u) {
#pragma unroll
    for (int r = 0; r < 4; ++r) {
      const float inv = __builtin_amdgcn_rcpf(lac[u][r]);
      const int trow = qb + u * 16 + g * 4 + r;
#pragma unroll
      for (int fd = 0; fd < 4; ++fd)
        Oc[(size_t)(b * 2048 + trow) * 1024 + h * 64 + fd * 16 + c] =
            f2bf(po[u][fd][r] * inv);
    }
  }
}

// ---------- launch ----------
extern "C" void kernel_launch(void* const* d_in, const int* in_sizes, int n_in,
                              void* d_out, int out_size, void* d_ws,
                              size_t ws_size, hipStream_t stream) {
  const float* x = (const float*)d_in[0];
  const float* Wq = (const float*)d_in[1];
  const float* Wk = (const float*)d_in[2];
  const float* Wv = (const float*)d_in[3];
  const float* Wo = (const float*)d_in[4];
  float* out = (float*)d_out;

  char* ws = (char*)d_ws;
  unsigned short* xb   = (unsigned short*)ws;                          // 16 MB
  unsigned short* Qb   = (unsigned short*)(ws + (size_t)(16u << 20));  // 16 MB
  unsigned short* Attn = (unsigned short*)(ws + (size_t)(32u << 20));  // 16 MB
  unsigned short* Wcat = (unsigned short*)(ws + (size_t)(48u << 20));  // 2.25 MB
  unsigned short* Wot  = (unsigned short*)(ws + (size_t)(48u << 20) + 2359296);
  unsigned short* Kb   = (unsigned short*)(ws + (size_t)(48u << 20) + 2359296 + 2097152);
  unsigned short* Vtb  = (unsigned short*)(ws + (size_t)(48u << 20) + 2359296 + 2097152 + 1048576);

  // 1) fused prep: x cast + all weight transposes (one launch)
  prep_all<<<dim3(32, 32, 4), dim3(32, 8), 0, stream>>>(x, Wq, Wk, Wv, Wo,
                                                        (ushort4*)xb, Wcat, Wot);

  // 2) fused QKV GEMM (V scattered directly into Vt [b][d][t])
  gemm_bt<0><<<dim3(9, 64), 256, 0, stream>>>(xb, Wcat, Qb, Kb, Vtb, nullptr,
                                              1152, 1024);

  // 3) causal MQA flash attention (4-wave blocks, 3/CU + backfill queue)
  attn_mqa<<<1024, 256, 0, stream>>>(Qb, Kb, Vtb, Attn);

  // 4) output projection: [8192][1024] x [1024][1024]^T -> fp32 d_out
  gemm_bt<1><<<dim3(8, 64), 256, 0, stream>>>(Attn, Wot, nullptr, nullptr,
                                              nullptr, out, 1024, 1024);
}